// Round 3
// baseline (212.550 us; speedup 1.0000x reference)
//
#include <hip/hip_runtime.h>

#define LSIZE 24
#define VOL (LSIZE*LSIZE*LSIZE*LSIZE)       // 331776 sites
#define NLINES (LSIZE*LSIZE*LSIZE)          // 13824 lines per direction
#define LPB 32                              // lines per block (4 waves x 8 lines)
#define TPB 256
#define ESTRIDE 71                          // element-plane stride (dwords); 71%32=7 -> ~2-way banks
#define BUFW (18*ESTRIDE)                   // dwords per wave buffer

// (o_re,o_im) = a * b, complex 3x3 matmul (row-major). Output must not alias inputs.
__device__ __forceinline__ void cmul(const float* __restrict__ ar, const float* __restrict__ ai,
                                     const float* __restrict__ br, const float* __restrict__ bi,
                                     float* __restrict__ or_, float* __restrict__ oi_) {
#pragma unroll
  for (int i = 0; i < 3; ++i) {
#pragma unroll
    for (int j = 0; j < 3; ++j) {
      float sr = 0.f, si = 0.f;
#pragma unroll
      for (int m = 0; m < 3; ++m) {
        float x = ar[i*3+m], y = ai[i*3+m];
        float u = br[m*3+j], v = bi[m*3+j];
        sr = fmaf(x, u, sr);
        sr = fmaf(-y, v, sr);
        si = fmaf(x, v, si);
        si = fmaf(y, u, si);
      }
      or_[i*3+j] = sr;
      oi_[i*3+j] = si;
    }
  }
}

__device__ __forceinline__ void cp9(float* dr, float* di, const float* sr, const float* si) {
#pragma unroll
  for (int e = 0; e < 9; ++e) { dr[e] = sr[e]; di[e] = si[e]; }
}

__device__ __forceinline__ void setid(float* r, float* im) {
#pragma unroll
  for (int e = 0; e < 9; ++e) { r[e] = (e == 0 || e == 4 || e == 8) ? 1.f : 0.f; im[e] = 0.f; }
}

__device__ __forceinline__ void shup(float* dr, float* di, const float* sr, const float* si, int delta) {
#pragma unroll
  for (int e = 0; e < 9; ++e) {
    dr[e] = __shfl_up(sr[e], (unsigned)delta, 64);
    di[e] = __shfl_up(si[e], (unsigned)delta, 64);
  }
}
__device__ __forceinline__ void shdn(float* dr, float* di, const float* sr, const float* si, int delta) {
#pragma unroll
  for (int e = 0; e < 9; ++e) {
    dr[e] = __shfl_down(sr[e], (unsigned)delta, 64);
    di[e] = __shfl_down(si[e], (unsigned)delta, 64);
  }
}

// Chunked cyclic scan, register-resident, zero __syncthreads.
//   thread (tl,ll): links k = 3tl..3tl+2 of line ll of its wave's octet.
//   B = U0*U1*U2; in-wave prefix/suffix scans of B (3+3 shuffle stages);
//   R = (B_{t+1}..B_7)*(B_0..B_{t-1});  P(3t+j) = locS_j * R * locA_{j-1}.
//   U's are RELOADED from global (L2-hot) for the output chain to keep the
//   scan's live set ~5 matrices -> fits the 128-VGPR budget of 4 blocks/CU.
//   mu!=3 stores go through a per-wave LDS transpose buffer (wave-local
//   lgkmcnt sync only) so each store instruction covers 64 consecutive dwords.
__global__ __launch_bounds__(TPB, 4) void polyakov_hyb(
    const float* __restrict__ U_re, const float* __restrict__ U_im,
    float* __restrict__ out) {
  __shared__ float buf[4 * BUFW];          // 4 waves * 5112 B = 20448 B

  const int lane = threadIdx.x & 63;
  const int wv   = threadIdx.x >> 6;
  const int mu   = (blockIdx.x * LPB) / NLINES;   // block-uniform (13824 % 32 == 0)

  int tl, ll, sh;
  if (mu == 3) { tl = lane & 7; ll = lane >> 3; sh = 1; }
  else         { tl = lane >> 3; ll = lane & 7; sh = 8; }

  const int l0 = blockIdx.x * LPB + wv * 8 - mu * NLINES;  // wave's octet base line
  const int l  = l0 + ll;
  const int cC = l % LSIZE;
  const int cB = (l / LSIZE) % LSIZE;
  const int cA = l / (LSIZE*LSIZE);

  int x0, x1, x2, x3, st;
  if (mu == 0)      { x0 = 0;  x1 = cA; x2 = cB; x3 = cC; st = LSIZE*LSIZE*LSIZE; }
  else if (mu == 1) { x0 = cA; x1 = 0;  x2 = cB; x3 = cC; st = LSIZE*LSIZE; }
  else if (mu == 2) { x0 = cA; x1 = cB; x2 = 0;  x3 = cC; st = LSIZE; }
  else              { x0 = cA; x1 = cB; x2 = cC; x3 = 0;  st = 1; }
  const int s0 = ((x0*LSIZE + x1)*LSIZE + x2)*LSIZE + x3;
  const int k0 = 3 * tl;

  const float* __restrict__ gR = U_re + (size_t)mu * (VOL*9);
  const float* __restrict__ gI = U_im + (size_t)mu * (VOL*9);
  float* __restrict__ oR = out + (size_t)mu * (VOL*9);
  float* __restrict__ oI = out + (size_t)(4 + mu) * (VOL*9);

  auto ldU = [&](int kk, float* r, float* im_) {
    const float* p = gR + (size_t)(s0 + kk*st) * 9;
    const float* q = gI + (size_t)(s0 + kk*st) * 9;
#pragma unroll
    for (int e = 0; e < 9; ++e) { r[e] = p[e]; im_[e] = q[e]; }
  };

  float* wbuf = buf + wv * BUFW;

  // emit one output matrix for slab (k0+j) of this thread's line
  auto emit = [&](const float* Vr, const float* Vi, int j) {
    if (mu == 3) {
      float* pr = oR + (size_t)(s0 + (k0 + j) * st) * 9;
      float* pi = oI + (size_t)(s0 + (k0 + j) * st) * 9;
#pragma unroll
      for (int e = 0; e < 9; ++e) { pr[e] = Vr[e]; pi[e] = Vi[e]; }
    } else {
      // wave-local transpose: matrix m = lane at plane-major [e][m]
      asm volatile("s_waitcnt lgkmcnt(0)" ::: "memory");  // buffer free (prev phase's reads done)
#pragma unroll
      for (int e = 0; e < 9; ++e) {
        wbuf[e * ESTRIDE + lane]       = Vr[e];
        wbuf[(9 + e) * ESTRIDE + lane] = Vi[e];
      }
      asm volatile("s_waitcnt lgkmcnt(0)" ::: "memory");  // writes visible to whole wave
      __builtin_amdgcn_sched_barrier(0);
      // coalesced read-out: dword d = lane + 64p of the 576-dword phase image,
      // image layout = global layout: [slab(8)][line(8)][e(9)] per array.
      const int s0w = s0 - ll;          // ll==0 line of the octet (e2==1 for mu!=3)
      int slab = 0, rem = lane;         // rem in [0,72)
#pragma unroll
      for (int p = 0; p < 9; ++p) {
        int line8 = rem / 9;
        int e = rem - line8 * 9;
        int m = (slab << 3) + line8;
        float vr = wbuf[e * ESTRIDE + m];
        float vi = wbuf[(9 + e) * ESTRIDE + m];
        size_t off = (size_t)(s0w + (3 * slab + j) * st) * 9 + rem;
        oR[off] = vr;
        oI[off] = vi;
        int rem2 = rem + 64;
        int c = rem2 >= 72;
        rem = c ? rem2 - 72 : rem2;
        slab += c;
      }
    }
  };

  // ---- B = U0*U1*U2 (U's not kept live) ----
  float Br[9], Bi[9];
  {
    float Ar[9], Ai[9], Cr[9], Ci[9], Tr0[9], Ti0[9];
    ldU(k0 + 0, Ar, Ai);
    ldU(k0 + 1, Cr, Ci);
    cmul(Ar, Ai, Cr, Ci, Tr0, Ti0);      // U0*U1
    ldU(k0 + 2, Ar, Ai);                 // U2
    cmul(Tr0, Ti0, Ar, Ai, Br, Bi);      // B
  }

  float Yr[9], Yi[9], Tr[9], Ti[9];

  // ---- inclusive prefix scan, then exclusive end P = B_0..B_{t-1} ----
  float Pr[9], Pi[9];
  {
    float Xr[9], Xi[9];
    cp9(Xr, Xi, Br, Bi);
#pragma unroll
    for (int d = 1; d < 8; d <<= 1) {
      shup(Yr, Yi, Xr, Xi, d * sh);
      if (tl >= d) { cmul(Yr, Yi, Xr, Xi, Tr, Ti); cp9(Xr, Xi, Tr, Ti); }
    }
    shup(Pr, Pi, Xr, Xi, sh);
    if (tl == 0) setid(Pr, Pi);
  }

  // ---- inclusive suffix scan, then exclusive end Q = B_{t+1}..B_7; R = Q*P ----
  float Rr[9], Ri[9];
  {
    float Zr[9], Zi[9];
    cp9(Zr, Zi, Br, Bi);
#pragma unroll
    for (int d = 1; d < 8; d <<= 1) {
      shdn(Yr, Yi, Zr, Zi, d * sh);
      if (tl + d < 8) { cmul(Zr, Zi, Yr, Yi, Tr, Ti); cp9(Zr, Zi, Tr, Ti); }
    }
    shdn(Yr, Yi, Zr, Zi, sh);            // Q
    if (tl == 7) setid(Yr, Yi);
    cmul(Yr, Yi, Pr, Pi, Rr, Ri);        // R = Q*P
  }

  // ---- outputs; reload U's (L2-hot) ----
  // out0 = B*R
  cmul(Br, Bi, Rr, Ri, Tr, Ti);
  emit(Tr, Ti, 0);                       // B dead

  float W2r[9], W2i[9], U1r[9], U1i[9];
  ldU(k0 + 2, Yr, Yi);                   // U2
  cmul(Yr, Yi, Rr, Ri, W2r, W2i);        // W2 = U2*R   (R dead)
  ldU(k0 + 1, U1r, U1i);                 // U1 (kept for out2)
  float W1r[9], W1i[9];
  cmul(U1r, U1i, W2r, W2i, W1r, W1i);    // W1 = U1*W2
  ldU(k0 + 0, Pr, Pi);                   // U0 (reuse P regs)

  cmul(W1r, W1i, Pr, Pi, Tr, Ti);        // out1 = W1*U0
  emit(Tr, Ti, 1);                       // W1 dead
  cmul(W2r, W2i, Pr, Pi, Yr, Yi);        // V = W2*U0   (W2, U0 dead)
  cmul(Yr, Yi, U1r, U1i, Tr, Ti);        // out2 = V*U1
  emit(Tr, Ti, 2);
}

extern "C" void kernel_launch(void* const* d_in, const int* in_sizes, int n_in,
                              void* d_out, int out_size, void* d_ws, size_t ws_size,
                              hipStream_t stream) {
  const float* U_re = (const float*)d_in[0];
  const float* U_im = (const float*)d_in[1];
  float* out = (float*)d_out;
  int nblocks = 4 * NLINES / LPB;   // 1728 blocks x 256 threads
  hipLaunchKernelGGL(polyakov_hyb, dim3(nblocks), dim3(TPB), 0, stream, U_re, U_im, out);
}

// Round 4
// 178.543 us; speedup vs baseline: 1.1905x; 1.1905x over previous
//
#include <hip/hip_runtime.h>

#define LSIZE 24
#define VOL (LSIZE*LSIZE*LSIZE*LSIZE)       // 331776 sites
#define NLINES (LSIZE*LSIZE*LSIZE)          // 13824 lines per direction
#define LPB 8                               // lines per block (= 1 wave)
#define TPB 64
#define IMG 1728                            // dwords per re/im image (8 lines * 24 slabs * 9)
#define NCHUNK 864                          // 16B chunks in the 2*IMG image

// (o_re,o_im) = a * b, complex 3x3 matmul (row-major). Output must not alias inputs.
__device__ __forceinline__ void cmul(const float* __restrict__ ar, const float* __restrict__ ai,
                                     const float* __restrict__ br, const float* __restrict__ bi,
                                     float* __restrict__ or_, float* __restrict__ oi_) {
#pragma unroll
  for (int i = 0; i < 3; ++i) {
#pragma unroll
    for (int j = 0; j < 3; ++j) {
      float sr = 0.f, si = 0.f;
#pragma unroll
      for (int m = 0; m < 3; ++m) {
        float x = ar[i*3+m], y = ai[i*3+m];
        float u = br[m*3+j], v = bi[m*3+j];
        sr = fmaf(x, u, sr);
        sr = fmaf(-y, v, sr);
        si = fmaf(x, v, si);
        si = fmaf(y, u, si);
      }
      or_[i*3+j] = sr;
      oi_[i*3+j] = si;
    }
  }
}

__device__ __forceinline__ void cp9(float* dr, float* di, const float* sr, const float* si) {
#pragma unroll
  for (int e = 0; e < 9; ++e) { dr[e] = sr[e]; di[e] = si[e]; }
}

__device__ __forceinline__ void setid(float* r, float* im) {
#pragma unroll
  for (int e = 0; e < 9; ++e) { r[e] = (e == 0 || e == 4 || e == 8) ? 1.f : 0.f; im[e] = 0.f; }
}

__device__ __forceinline__ void shup(float* dr, float* di, const float* sr, const float* si, int delta) {
#pragma unroll
  for (int e = 0; e < 9; ++e) {
    dr[e] = __shfl_up(sr[e], (unsigned)delta, 64);
    di[e] = __shfl_up(si[e], (unsigned)delta, 64);
  }
}
__device__ __forceinline__ void shdn(float* dr, float* di, const float* sr, const float* si, int delta) {
#pragma unroll
  for (int e = 0; e < 9; ++e) {
    dr[e] = __shfl_down(sr[e], (unsigned)delta, 64);
    di[e] = __shfl_down(si[e], (unsigned)delta, 64);
  }
}

__device__ __forceinline__ void ldm9(const float* __restrict__ L, float* v) {
#pragma unroll
  for (int e = 0; e < 9; ++e) v[e] = L[e];
}
__device__ __forceinline__ void stm9(float* __restrict__ L, const float* v) {
#pragma unroll
  for (int e = 0; e < 9; ++e) L[e] = v[e];
}

// One wave per block, 8 lines, zero __syncthreads.
//   LDS image = exact global byte order of the tile (16B-aligned runs for all mu
//   because 24 % 8 == 0 -> no cC wrap inside a block).
//   stage-in : global_load_lds width 16 (async, no VGPR roundtrip)
//   compute  : thread (tl,ll) owns links 3tl..3tl+2 of line ll; B = U0*U1*U2;
//              in-wave shuffle scans; R = (B_{t+1}..B_7)(B_0..B_{t-1});
//              P(3t+j) = locS_j * R * locA_{j-1}; results overwrite the
//              thread's own image slots (single-owner -> in-place safe)
//   stage-out: ds_read_b128 + aligned global_store_dwordx4 (1 KiB/instr)
__global__ __launch_bounds__(TPB, 3) void polyakov_1w(
    const float* __restrict__ U_re, const float* __restrict__ U_im,
    float* __restrict__ out) {
  __shared__ __align__(16) float lds[2 * IMG];   // 13824 B

  const int lane = threadIdx.x;
  const int bid  = blockIdx.x;
  const int mu   = bid / (NLINES / LPB);
  const int l0   = (bid - mu * (NLINES / LPB)) * LPB;

  const int cC0 = l0 % LSIZE;
  const int cB0 = (l0 / LSIZE) % LSIZE;
  const int cA0 = l0 / (LSIZE * LSIZE);

  int s00, st;
  if (mu == 0)      { s00 = l0;                                st = 13824; }
  else if (mu == 1) { s00 = cA0*13824 + cB0*24  + cC0;         st = 576;   }
  else if (mu == 2) { s00 = cA0*13824 + cB0*576 + cC0;         st = 24;    }
  else              { s00 = l0 * 24;                           st = 1;     }

  const float* __restrict__ gR = U_re + (size_t)mu * (VOL*9);
  const float* __restrict__ gI = U_im + (size_t)mu * (VOL*9);

  // ---------------- stage in (async, direct to LDS) ----------------
#pragma unroll
  for (int p = 0; p < 14; ++p) {
    int c = p * 64 + lane;                 // 16B chunk id
    if (c < NCHUNK) {
      int d   = c << 2;                    // dword index in image
      int arr = d >= IMG;
      int da  = d - (arr ? IMG : 0);
      int g;
      if (mu == 3) g = s00 * 9 + da;       // whole tile is one contiguous run
      else { int slab = da / 72; g = (s00 + slab * st) * 9 + (da - slab * 72); }
      const float* src = (arr ? gI : gR) + g;
      __builtin_amdgcn_global_load_lds(
          (const __attribute__((address_space(1))) void*)(const void*)src,
          (__attribute__((address_space(3))) void*)(void*)(lds + p * 256),
          16, 0, 0);
    }
  }
  asm volatile("s_waitcnt vmcnt(0)" ::: "memory");
  __builtin_amdgcn_sched_barrier(0);

  // ---------------- compute ----------------
  const int tl = lane >> 3;                // chunk index along line
  const int ll = lane & 7;                 // line within block
  const int k0 = 3 * tl;
  const int uo = (mu == 3) ? ll * 216 : ll * 9;
  const int ks = (mu == 3) ? 9 : 72;       // dword stride between slabs
  float* mR = lds + uo;
  float* mI = lds + IMG + uo;

  float Br[9], Bi[9], Yr[9], Yi[9], Tr[9], Ti[9];
  {
    float Ar[9], Ai[9];
    ldm9(mR + (k0+0)*ks, Yr); ldm9(mI + (k0+0)*ks, Yi);   // U0
    ldm9(mR + (k0+1)*ks, Ar); ldm9(mI + (k0+1)*ks, Ai);   // U1
    cmul(Yr, Yi, Ar, Ai, Tr, Ti);                         // U0*U1
    ldm9(mR + (k0+2)*ks, Ar); ldm9(mI + (k0+2)*ks, Ai);   // U2
    cmul(Tr, Ti, Ar, Ai, Br, Bi);                         // B
  }

  // inclusive prefix scan -> exclusive end P = B_0..B_{t-1}
  float Pr[9], Pi[9];
  {
    float Xr[9], Xi[9];
    cp9(Xr, Xi, Br, Bi);
#pragma unroll
    for (int d = 1; d < 8; d <<= 1) {
      shup(Yr, Yi, Xr, Xi, 8 * d);
      if (tl >= d) { cmul(Yr, Yi, Xr, Xi, Tr, Ti); cp9(Xr, Xi, Tr, Ti); }
    }
    shup(Pr, Pi, Xr, Xi, 8);
    if (tl == 0) setid(Pr, Pi);
  }
  // inclusive suffix scan -> exclusive end Q = B_{t+1}..B_7 ; R = Q*P
  float Rr[9], Ri[9];
  {
    float Zr[9], Zi[9];
    cp9(Zr, Zi, Br, Bi);
#pragma unroll
    for (int d = 1; d < 8; d <<= 1) {
      shdn(Yr, Yi, Zr, Zi, 8 * d);
      if (tl + d < 8) { cmul(Zr, Zi, Yr, Yi, Tr, Ti); cp9(Zr, Zi, Tr, Ti); }
    }
    shdn(Yr, Yi, Zr, Zi, 8);
    if (tl == 7) setid(Yr, Yi);
    cmul(Yr, Yi, Pr, Pi, Rr, Ri);          // R
  }

  // outputs (each slot read-complete before overwrite; single-owner slots)
  ldm9(mR + (k0+0)*ks, Pr); ldm9(mI + (k0+0)*ks, Pi);     // U0 (reload before slot0 write)
  cmul(Br, Bi, Rr, Ri, Tr, Ti);                           // out0 = B*R
  stm9(mR + (k0+0)*ks, Tr); stm9(mI + (k0+0)*ks, Ti);

  float W2r[9], W2i[9], U1r[9], U1i[9], W1r[9], W1i[9];
  ldm9(mR + (k0+2)*ks, Yr); ldm9(mI + (k0+2)*ks, Yi);     // U2
  cmul(Yr, Yi, Rr, Ri, W2r, W2i);                         // W2 = U2*R
  ldm9(mR + (k0+1)*ks, U1r); ldm9(mI + (k0+1)*ks, U1i);   // U1
  cmul(U1r, U1i, W2r, W2i, W1r, W1i);                     // W1 = U1*W2
  cmul(W1r, W1i, Pr, Pi, Tr, Ti);                         // out1 = W1*U0
  stm9(mR + (k0+1)*ks, Tr); stm9(mI + (k0+1)*ks, Ti);
  cmul(W2r, W2i, Pr, Pi, Yr, Yi);                         // V = W2*U0
  cmul(Yr, Yi, U1r, U1i, Tr, Ti);                         // out2 = V*U1
  stm9(mR + (k0+2)*ks, Tr); stm9(mI + (k0+2)*ks, Ti);

  asm volatile("s_waitcnt lgkmcnt(0)" ::: "memory");
  __builtin_amdgcn_sched_barrier(0);

  // ---------------- stage out (aligned 16B vectors) ----------------
  float* __restrict__ oR = out + (size_t)mu * (VOL*9);
  float* __restrict__ oI = out + (size_t)(4 + mu) * (VOL*9);
#pragma unroll
  for (int p = 0; p < 14; ++p) {
    int c = p * 64 + lane;
    if (c < NCHUNK) {
      int d   = c << 2;
      int arr = d >= IMG;
      int da  = d - (arr ? IMG : 0);
      int g;
      if (mu == 3) g = s00 * 9 + da;
      else { int slab = da / 72; g = (s00 + slab * st) * 9 + (da - slab * 72); }
      float4 v = *(const float4*)(lds + d);
      *(float4*)((arr ? oI : oR) + g) = v;
    }
  }
}

extern "C" void kernel_launch(void* const* d_in, const int* in_sizes, int n_in,
                              void* d_out, int out_size, void* d_ws, size_t ws_size,
                              hipStream_t stream) {
  const float* U_re = (const float*)d_in[0];
  const float* U_im = (const float*)d_in[1];
  float* out = (float*)d_out;
  int nblocks = 4 * NLINES / LPB;   // 6912 blocks x 64 threads
  hipLaunchKernelGGL(polyakov_1w, dim3(nblocks), dim3(TPB), 0, stream, U_re, U_im, out);
}